// Round 17
// baseline (423.035 us; speedup 1.0000x reference)
//
#include <hip/hip_runtime.h>

#define KCODES 4096
#define DIM    256
#define NROWS  65536
#define MARGIN 4.0e-4f
#define DSLACK 4.0e-5f
#define QDELT  4.0e-5f      // u4 quantum (round-15 validated)
#define LCAP   2048
#define CPAD   32
#define LSTRIDE (DIM + 4)

typedef unsigned long long u64;
typedef unsigned int  uint;
typedef unsigned short ushort;
typedef __attribute__((ext_vector_type(8))) short bf16x8;
typedef __attribute__((ext_vector_type(4))) float f32x4;

typedef __attribute__((address_space(3))) uint lds_u32_t;
typedef __attribute__((address_space(1))) uint glb_u32_t;

__device__ __forceinline__ void g2lds16(const void* g, void* l) {
    __builtin_amdgcn_global_load_lds((const glb_u32_t*)g, (lds_u32_t*)l, 16, 0, 0);
}

// butterfly min across 16-lane row (result broadcast to all 16 lanes)
__device__ __forceinline__ float dppmin_row16(float m) {
    m = fminf(m, __int_as_float(__builtin_amdgcn_update_dpp(0, __float_as_int(m), 0xB1, 0xF, 0xF, true)));
    m = fminf(m, __int_as_float(__builtin_amdgcn_update_dpp(0, __float_as_int(m), 0x4E, 0xF, 0xF, true)));
    m = fminf(m, __int_as_float(__builtin_amdgcn_update_dpp(0, __float_as_int(m), 0x124, 0xF, 0xF, true)));
    m = fminf(m, __int_as_float(__builtin_amdgcn_update_dpp(0, __float_as_int(m), 0x128, 0xF, 0xF, true)));
    return m;
}

// ============================ shared helpers ============================

__device__ __forceinline__ float np_half_sum128(const float4* __restrict__ p4) {
    #pragma clang fp contract(off)
    float4 v0 = p4[0], v1 = p4[1];
    float r0 = v0.x * v0.x, r1 = v0.y * v0.y, r2 = v0.z * v0.z, r3 = v0.w * v0.w;
    float r4 = v1.x * v1.x, r5 = v1.y * v1.y, r6 = v1.z * v1.z, r7 = v1.w * v1.w;
    #pragma unroll
    for (int i = 1; i < 16; ++i) {
        float4 a = p4[2 * i], b = p4[2 * i + 1];
        r0 += a.x * a.x; r1 += a.y * a.y; r2 += a.z * a.z; r3 += a.w * a.w;
        r4 += b.x * b.x; r5 += b.y * b.y; r6 += b.z * b.z; r7 += b.w * b.w;
    }
    return ((r0 + r1) + (r2 + r3)) + ((r4 + r5) + (r6 + r7));
}

__global__ void k_rownorm(const float* __restrict__ src, float* __restrict__ dst, int nrows) {
    int r = blockIdx.x * blockDim.x + threadIdx.x;
    if (r >= nrows) return;
    const float4* p4 = (const float4*)(src + (size_t)r * DIM);
    float s;
    {
        #pragma clang fp contract(off)
        s = np_half_sum128(p4) + np_half_sum128(p4 + 32);
    }
    dst[r] = s;
}

// validated (round 3): fl32( fl32(Cr+ebc) - fl32(2*fl32(cross_exact)) )
__device__ __forceinline__ float f32_dist(float Cr, float ebc, double accv) {
    #pragma clang fp contract(off)
    float A = Cr + ebc;
    float B = 2.0f * (float)accv;
    return A - B;
}

__device__ __forceinline__ ushort f2bf(float f) {
    uint u = __float_as_uint(f);
    return (ushort)((u + 0x7fffu + ((u >> 16) & 1u)) >> 16);
}

__device__ __forceinline__ uint4 pack8(float4 a, float4 b) {
    uint4 ov;
    ov.x = (uint)f2bf(a.x) | ((uint)f2bf(a.y) << 16);
    ov.y = (uint)f2bf(a.z) | ((uint)f2bf(a.w) << 16);
    ov.z = (uint)f2bf(b.x) | ((uint)f2bf(b.y) << 16);
    ov.w = (uint)f2bf(b.z) | ((uint)f2bf(b.w) << 16);
    return ov;
}

// ============================ fast-path kernels ============================

// fused split + np-faithful rownorm: one pass over src.
__global__ void k_prep(const float* __restrict__ src, ushort* __restrict__ dst,
                       float* __restrict__ nrm, int nrows) {
    int r = blockIdx.x * blockDim.x + threadIdx.x;
    if (r >= nrows) return;
    const float4* p4 = (const float4*)(src + (size_t)r * DIM);
    uint4* d4 = (uint4*)(dst + (size_t)r * DIM);
    float h[2];
    #pragma unroll
    for (int half = 0; half < 2; ++half) {
        #pragma clang fp contract(off)
        const float4* p = p4 + half * 32;
        float4 v0 = p[0], v1 = p[1];
        d4[half * 16] = pack8(v0, v1);
        float r0 = v0.x * v0.x, r1 = v0.y * v0.y, r2 = v0.z * v0.z, r3 = v0.w * v0.w;
        float r4 = v1.x * v1.x, r5 = v1.y * v1.y, r6 = v1.z * v1.z, r7 = v1.w * v1.w;
        #pragma unroll
        for (int i = 1; i < 16; ++i) {
            float4 a = p[2 * i], b = p[2 * i + 1];
            d4[half * 16 + i] = pack8(a, b);
            r0 += a.x * a.x; r1 += a.y * a.y; r2 += a.z * a.z; r3 += a.w * a.w;
            r4 += b.x * b.x; r5 += b.y * b.y; r6 += b.z * b.z; r7 += b.w * b.w;
        }
        h[half] = ((r0 + r1) + (r2 + r3)) + ((r4 + r5) + (r6 + r7));
    }
    {
        #pragma clang fp contract(off)
        nrm[r] = h[0] + h[1];
    }
}

__global__ void k_init(int* __restrict__ cnt) {
    cnt[blockIdx.x * 256 + threadIdx.x] = 0;
}

// MFMA filter, CODES-IN-REGISTERS: each wave holds 64 codes x 256K as B-frags
// (128 VGPR); z streams through LDS as 32-row swizzled dbuf tiles (2x16KB,
// 2 blocks/CU => 8 waves/CU but only 8MB/CU LDS reads vs 16MB before).
// Grid 512: cgb = bid>>5 (256-code block), zsl = bid&31 (2048-row slice).
// tk granularity: 64-code tiles (one per wave), subtile = 16 CONTIGUOUS codes
// (= one cg), u4 deltas (quantum 4e-5) packed in u16.
__global__ __launch_bounds__(256, 2)
void k_gemm(const ushort* __restrict__ zh, const ushort* __restrict__ eh,
            const float* __restrict__ Crow, const float* __restrict__ eb2,
            float* __restrict__ tk, ushort* __restrict__ tk2) {
    __shared__ __align__(16) ushort Zs[2][32 * 256];   // 2 x 16KB

    const int t = threadIdx.x;
    const int lane = t & 63;
    const int w = t >> 6;
    const int l15 = lane & 15, l4 = lane >> 4;
    const int cgb = blockIdx.x >> 5;
    const int zsl = blockIdx.x & 31;
    const int code0w = cgb * 256 + w * 64;   // wave's 64 codes
    const int tt = cgb * 4 + w;              // wave's tk tile (0..63)
    const int row0s = zsl * 2048;

    const char* zbp = (const char*)zh + (size_t)row0s * 512;

    // stage 32-row z-tile: linear LDS dest, inverse-swizzled source
    auto stage = [&](int buf, int zt) {
        const char* base = zbp + (size_t)zt * 32 * 512;
        #pragma unroll
        for (int i = 0; i < 4; ++i) {
            int idx = i * 256 + t;            // 0..1023 16B-chunks
            int row = idx >> 5;
            int c16 = idx & 31;
            int src = (row << 9) + ((c16 ^ (row & 7)) << 4);
            g2lds16(base + src, (char*)Zs[buf] + idx * 16);
        }
    };

    // ---- B: 64 codes x 256 K in registers (MFMA B-frag layout), 128 VGPR ----
    bf16x8 b[4][8];
    #pragma unroll
    for (int cg = 0; cg < 4; ++cg)
        #pragma unroll
        for (int ks = 0; ks < 8; ++ks)
            b[cg][ks] = *(const bf16x8*)&eh[(size_t)(code0w + cg * 16 + l15) * 256 + ks * 32 + l4 * 8];

    float ebv[4];
    #pragma unroll
    for (int cg = 0; cg < 4; ++cg) ebv[cg] = eb2[code0w + cg * 16 + l15];

    const f32x4 fzero = (f32x4){0.f, 0.f, 0.f, 0.f};

    stage(0, 0);
    __syncthreads();

    for (int zt = 0; zt < 64; ++zt) {
        int buf = zt & 1;
        if (zt < 63) stage(buf ^ 1, zt + 1);

        float crf[8];
        #pragma unroll
        for (int f = 0; f < 2; ++f)
            #pragma unroll
            for (int rg = 0; rg < 4; ++rg)
                crf[f * 4 + rg] = Crow[row0s + zt * 32 + f * 16 + l4 * 4 + rg];

        f32x4 acc[2][4];
        const ushort* Zb = Zs[buf];
        #pragma unroll
        for (int ks = 0; ks < 8; ++ks) {
            bf16x8 af[2];
            #pragma unroll
            for (int f = 0; f < 2; ++f) {
                int rA = f * 16 + l15;
                int off = rA * 256 + ((ks * 32 + l4 * 8) ^ ((l15 & 7) << 3));
                af[f] = *(const bf16x8*)&Zb[off];
            }
            __builtin_amdgcn_s_setprio(1);
            #pragma unroll
            for (int f = 0; f < 2; ++f)
                #pragma unroll
                for (int cg = 0; cg < 4; ++cg)
                    acc[f][cg] = __builtin_amdgcn_mfma_f32_16x16x32_bf16(
                        af[f], b[cg][ks], ks == 0 ? fzero : acc[f][cg], 0, 0, 0);
            __builtin_amdgcn_s_setprio(0);
        }

        // epilogue: subtile = cg (16 contiguous codes, lane dim); Cr-free mins.
        // dppmin_row16 broadcasts, so every lane holds all 4 subtile mins.
        #pragma unroll
        for (int f = 0; f < 2; ++f) {
            #pragma unroll
            for (int rg = 0; rg < 4; ++rg) {
                float m0 = dppmin_row16(fmaf(-2.0f, acc[f][0][rg], ebv[0]));
                float m1 = dppmin_row16(fmaf(-2.0f, acc[f][1][rg], ebv[1]));
                float m2 = dppmin_row16(fmaf(-2.0f, acc[f][2][rg], ebv[2]));
                float m3 = dppmin_row16(fmaf(-2.0f, acc[f][3][rg], ebv[3]));
                float mt = fminf(fminf(m0, m1), fminf(m2, m3));
                int q0 = (int)((m0 - mt) * 2.5e4f); q0 = q0 > 15 ? 15 : q0;
                int q1 = (int)((m1 - mt) * 2.5e4f); q1 = q1 > 15 ? 15 : q1;
                int q2 = (int)((m2 - mt) * 2.5e4f); q2 = q2 > 15 ? 15 : q2;
                int q3 = (int)((m3 - mt) * 2.5e4f); q3 = q3 > 15 ? 15 : q3;
                uint pkv = (uint)q0 | ((uint)q1 << 4) | ((uint)q2 << 8) | ((uint)q3 << 12);
                if (l15 == 0) {
                    int grow = row0s + zt * 32 + f * 16 + l4 * 4 + rg;
                    tk [(size_t)tt * NROWS + grow] = crf[f * 4 + rg] + mt;
                    tk2[(size_t)tt * NROWS + grow] = (ushort)pkv;
                }
            }
        }
        __syncthreads();
    }
}

// per row: rowbest over 64 tile-mins; decode 4 u4 subtile deltas per tile;
// wave-aggregated append to 256 per-subtile lists; padded counters; init fkey.
__global__ void k_lists(const float* __restrict__ tk, const ushort* __restrict__ tk2,
                        int* __restrict__ cnt, int* __restrict__ list,
                        u64* __restrict__ fkey) {
    int row = blockIdx.x * 256 + threadIdx.x;
    int lane = threadIdx.x & 63;
    float tm[64]; uint pk[64];
    #pragma unroll
    for (int tt = 0; tt < 64; ++tt) {
        tm[tt] = tk [(size_t)tt * NROWS + row];
        pk[tt] = tk2[(size_t)tt * NROWS + row];
    }
    float best = tm[0];
    #pragma unroll
    for (int tt = 1; tt < 64; ++tt) best = fminf(best, tm[tt]);
    fkey[row] = ~0ull;
    float cutoff = best + (MARGIN + DSLACK);

    #pragma unroll
    for (int tt = 0; tt < 64; ++tt) {
        #pragma unroll
        for (int p = 0; p < 4; ++p) {
            float v = tm[tt] + (float)((pk[tt] >> (4 * p)) & 15u) * QDELT;
            bool pred = v <= cutoff;
            u64 mask = __ballot(pred);
            if (mask) {
                int sub = tt * 4 + p;
                int nq = __popcll(mask);
                int rank = __popcll(mask & ((1ull << lane) - 1ull));
                int base = 0;
                if (lane == 0) base = atomicAdd(&cnt[sub * CPAD], nq);
                base = __shfl(base, 0, 64);
                int pos = base + rank;
                if (pred && pos < LCAP) list[sub * LCAP + pos] = row;
            }
        }
    }
}

// exact decider; sub covers the 16 CONTIGUOUS codes [sub*16, sub*16+16).
// Validated f64-cross + f32_dist + lexicographic (d,idx) key, atomicMin-merged.
__global__ __launch_bounds__(256, 2)
void k_exact(const float* __restrict__ z, const float* __restrict__ e,
             const float* __restrict__ Crow, const float* __restrict__ eb2,
             const int* __restrict__ list, const int* __restrict__ cnt,
             u64* __restrict__ fkey) {
    __shared__ __align__(16) float ex[16][260];
    __shared__ __align__(16) float zx[32][260];
    __shared__ int rows[32];
    __shared__ u64 keytab[32][17];
    const int sub = blockIdx.x;       // 0..255
    const int nct = cnt[sub * CPAD];
    const int t = threadIdx.x;
    const int rp = t & 15, cs = t >> 4;   // cs 0..15: one code each

    {   // stage e subtile (16 contiguous codes x 256)
        int cc = t >> 4, c16 = t & 15;
        const float4* src = (const float4*)(e + (size_t)(sub * 16 + cc) * DIM);
        float4* dr = (float4*)ex[cc];
        #pragma unroll
        for (int j = 0; j < 4; ++j) dr[c16 + 16 * j] = src[c16 + 16 * j];
    }
    const int gc0 = sub * 16 + cs;
    const float ebc0 = eb2[gc0];

    for (int base = blockIdx.y * 32; base < nct; base += gridDim.y * 32) {
        __syncthreads();
        if (t < 32) {
            int i = base + t;
            rows[t] = list[sub * LCAP + (i < nct ? i : nct - 1)];
        }
        __syncthreads();
        {
            int rr = t >> 3, c8 = t & 7;
            const float4* src = (const float4*)(z + (size_t)rows[rr] * DIM);
            float4* dr = (float4*)zx[rr];
            #pragma unroll
            for (int j = 0; j < 8; ++j) dr[c8 + 8 * j] = src[c8 + 8 * j];
        }
        __syncthreads();

        double a0 = 0.0, a1 = 0.0;
        const float4* z0 = (const float4*)zx[rp];
        const float4* z1 = (const float4*)zx[rp + 16];
        const float4* e0 = (const float4*)ex[cs];
        #pragma unroll 8
        for (int d4 = 0; d4 < 64; ++d4) {
            float4 x0 = z0[d4], x1 = z1[d4], y0 = e0[d4];
            a0 += (double)x0.x * (double)y0.x; a0 += (double)x0.y * (double)y0.y;
            a0 += (double)x0.z * (double)y0.z; a0 += (double)x0.w * (double)y0.w;
            a1 += (double)x1.x * (double)y0.x; a1 += (double)x1.y * (double)y0.y;
            a1 += (double)x1.z * (double)y0.z; a1 += (double)x1.w * (double)y0.w;
        }
        int r0 = rows[rp], r1 = rows[rp + 16];
        float C0 = Crow[r0], C1 = Crow[r1];
        keytab[rp][cs]      = ((u64)__float_as_uint(f32_dist(C0, ebc0, a0)) << 32) | (u64)gc0;
        keytab[rp + 16][cs] = ((u64)__float_as_uint(f32_dist(C1, ebc0, a1)) << 32) | (u64)gc0;
        __syncthreads();
        if (t < 32) {
            u64 kb = keytab[t][0];
            #pragma unroll
            for (int j = 1; j < 16; ++j) {
                u64 k = keytab[t][j];
                kb = k < kb ? k : kb;
            }
            atomicMin((unsigned long long*)&fkey[rows[t]], kb);
        }
    }
}

// gather quantized rows + indices; loss partial directly from fkey's exact
// f32 distances (error ~1e-7 relative vs elementwise ref).
__global__ __launch_bounds__(256)
void k_gather(const float* __restrict__ e, const u64* __restrict__ fkey,
              float* __restrict__ out, double* __restrict__ partial) {
    __shared__ double s[32];
    const int t = threadIdx.x;
    const int row = blockIdx.x * 32 + (t >> 3);
    const int c8 = t & 7;
    u64 key = fkey[row];
    const int idx = (int)(key & 0xffffffffull);
    if (c8 == 0) out[1 + (size_t)NROWS * DIM + row] = (float)idx;
    const float4* er = (const float4*)(e + (size_t)idx * DIM);
    float4* orow = (float4*)(out + 1 + (size_t)row * DIM);
    #pragma unroll
    for (int j = 0; j < 8; ++j) orow[c8 + 8 * j] = er[c8 + 8 * j];
    if (t < 32) {
        u64 k2 = fkey[blockIdx.x * 32 + t];
        s[t] = (double)__uint_as_float((uint)(k2 >> 32));
    }
    __syncthreads();
    if (t == 0) {
        double a = 0.0;
        #pragma unroll
        for (int i = 0; i < 32; ++i) a += s[i];
        partial[blockIdx.x] = a;
    }
}

__global__ void k_finish(const double* __restrict__ partial, float* __restrict__ out, int n) {
    __shared__ double s[256];
    double a = 0.0;
    for (int i = threadIdx.x; i < n; i += 256) a += partial[i];
    s[threadIdx.x] = a;
    __syncthreads();
    for (int off = 128; off > 0; off >>= 1) {
        if (threadIdx.x < off) s[threadIdx.x] += s[threadIdx.x + off];
        __syncthreads();
    }
    if (threadIdx.x == 0)
        out[0] = (float)(1.25 * s[0] / ((double)NROWS * (double)DIM));
}

// ===================== fallback (round-3 validated path) =====================

__global__ __launch_bounds__(256, 1)
void k_main_slow(const float* __restrict__ z, const float* __restrict__ e,
                 const float* __restrict__ Crow, const float* __restrict__ eb2,
                 float* __restrict__ out, double* __restrict__ partial) {
    __shared__ float  zt[64][LSTRIDE];
    __shared__ float  et[64][LSTRIDE];
    __shared__ float  redd[64][17];
    __shared__ int    redi[64][17];
    __shared__ int    bsel[64];
    __shared__ double lred[4];

    const int t  = threadIdx.x;
    const int tx = t & 15;
    const int ty = t >> 4;
    const int row0 = blockIdx.x * 64;

    {
        const float4* zsrc = (const float4*)(z + (size_t)row0 * DIM);
        for (int i = t; i < 64 * (DIM / 4); i += 256) {
            int r = i >> 6, c4 = i & 63;
            *(float4*)&zt[r][c4 * 4] = zsrc[r * (DIM / 4) + c4];
        }
    }
    float Cr[4];
    #pragma unroll
    for (int ri = 0; ri < 4; ++ri) Cr[ri] = Crow[row0 + ty * 4 + ri];
    float bestd[4]; int besti[4];
    #pragma unroll
    for (int ri = 0; ri < 4; ++ri) { bestd[ri] = __int_as_float(0x7f800000); besti[ri] = 0; }

    for (int kt = 0; kt < KCODES / 64; ++kt) {
        __syncthreads();
        {
            const float4* esrc = (const float4*)(e + (size_t)kt * 64 * DIM);
            for (int i = t; i < 64 * (DIM / 4); i += 256) {
                int r = i >> 6, c4 = i & 63;
                *(float4*)&et[r][c4 * 4] = esrc[r * (DIM / 4) + c4];
            }
        }
        __syncthreads();
        double acc[4][4];
        #pragma unroll
        for (int a = 0; a < 4; ++a)
            #pragma unroll
            for (int b = 0; b < 4; ++b) acc[a][b] = 0.0;
        #pragma unroll 4
        for (int d4 = 0; d4 < DIM / 4; ++d4) {
            float4 za[4], ea[4];
            #pragma unroll
            for (int ri = 0; ri < 4; ++ri) za[ri] = *(const float4*)&zt[ty * 4 + ri][d4 * 4];
            #pragma unroll
            for (int ci = 0; ci < 4; ++ci) ea[ci] = *(const float4*)&et[tx + 16 * ci][d4 * 4];
            #pragma unroll
            for (int ri = 0; ri < 4; ++ri)
                #pragma unroll
                for (int ci = 0; ci < 4; ++ci)
                    acc[ri][ci] += (double)za[ri].x * (double)ea[ci].x
                                 + (double)za[ri].y * (double)ea[ci].y
                                 + (double)za[ri].z * (double)ea[ci].z
                                 + (double)za[ri].w * (double)ea[ci].w;
        }
        #pragma unroll
        for (int ci = 0; ci < 4; ++ci) {
            int c = kt * 64 + tx + 16 * ci;
            float ebc = eb2[c];
            #pragma unroll
            for (int ri = 0; ri < 4; ++ri) {
                float d = f32_dist(Cr[ri], ebc, acc[ri][ci]);
                if (d < bestd[ri]) { bestd[ri] = d; besti[ri] = c; }
            }
        }
    }
    __syncthreads();
    #pragma unroll
    for (int ri = 0; ri < 4; ++ri) {
        redd[ty * 4 + ri][tx] = bestd[ri];
        redi[ty * 4 + ri][tx] = besti[ri];
    }
    __syncthreads();
    if (t < 64) {
        float bd = redd[t][0]; int bi = redi[t][0];
        for (int j = 1; j < 16; ++j) {
            float d = redd[t][j]; int i2 = redi[t][j];
            if (d < bd || (d == bd && i2 < bi)) { bd = d; bi = i2; }
        }
        bsel[t] = bi;
        out[1 + (size_t)NROWS * DIM + row0 + t] = (float)bi;
    }
    __syncthreads();
    double lacc = 0.0;
    {
        int r = t >> 2, qd = (t & 3) * 64;
        int bi = bsel[r];
        const float* qrow = e + (size_t)bi * DIM + qd;
        float* orow = out + 1 + (size_t)(row0 + r) * DIM + qd;
        #pragma unroll 4
        for (int d = 0; d < 64; ++d) {
            float qv = qrow[d], zv = zt[r][qd + d];
            double df = (double)qv - (double)zv;
            lacc += df * df;
            orow[d] = qv;
        }
    }
    for (int off = 32; off > 0; off >>= 1) lacc += __shfl_down(lacc, off, 64);
    if ((t & 63) == 0) lred[t >> 6] = lacc;
    __syncthreads();
    if (t == 0) partial[blockIdx.x] = lred[0] + lred[1] + lred[2] + lred[3];
}

// ============================ launch ============================

extern "C" void kernel_launch(void* const* d_in, const int* in_sizes, int n_in,
                              void* d_out, int out_size, void* d_ws, size_t ws_size,
                              hipStream_t stream) {
    const float* z = (const float*)d_in[0];
    const float* e = (const float*)d_in[1];
    float* out = (float*)d_out;
    char* w = (char*)d_ws;

    size_t o = 0;
    auto take = [&](size_t b) { size_t r = o; o = (o + b + 255) & ~(size_t)255; return r; };
    size_t o_zh = take((size_t)NROWS * DIM * 2);
    size_t o_eh = take((size_t)KCODES * DIM * 2);
    size_t o_cr = take((size_t)NROWS * 4);
    size_t o_eb = take((size_t)KCODES * 4);
    size_t o_tk = take((size_t)64 * NROWS * 4);
    size_t o_t2 = take((size_t)64 * NROWS * 2);
    size_t o_fk = take((size_t)NROWS * 8);
    size_t o_cn = take((size_t)256 * CPAD * 4);
    size_t o_ls = take((size_t)256 * LCAP * 4);
    size_t o_pt = take((size_t)2048 * 8);
    size_t need = o;

    if (ws_size >= need) {
        ushort* zh = (ushort*)(w + o_zh);
        ushort* eh = (ushort*)(w + o_eh);
        float* Cr  = (float*)(w + o_cr);
        float* eb  = (float*)(w + o_eb);
        float* tk  = (float*)(w + o_tk);
        ushort* tk2 = (ushort*)(w + o_t2);
        u64*   fk  = (u64*)(w + o_fk);
        int*   cn  = (int*)(w + o_cn);
        int*   ls  = (int*)(w + o_ls);
        double* pt = (double*)(w + o_pt);

        k_prep<<<NROWS / 256, 256, 0, stream>>>(z, zh, Cr, NROWS);
        k_prep<<<KCODES / 256, 256, 0, stream>>>(e, eh, eb, KCODES);
        k_init<<<(256 * CPAD) / 256, 256, 0, stream>>>(cn);
        k_gemm<<<512, 256, 0, stream>>>(zh, eh, Cr, eb, tk, tk2);
        k_lists<<<NROWS / 256, 256, 0, stream>>>(tk, tk2, cn, ls, fk);
        dim3 ge(256, 8);
        k_exact<<<ge, 256, 0, stream>>>(z, e, Cr, eb, ls, cn, fk);
        k_gather<<<NROWS / 32, 256, 0, stream>>>(e, fk, out, pt);
        k_finish<<<1, 256, 0, stream>>>(pt, out, 2048);
    } else {
        float* Cr  = (float*)w;
        float* eb  = Cr + NROWS;
        double* pt = (double*)(eb + KCODES);
        k_rownorm<<<NROWS / 256, 256, 0, stream>>>(z, Cr, NROWS);
        k_rownorm<<<KCODES / 256, 256, 0, stream>>>(e, eb, KCODES);
        k_main_slow<<<NROWS / 64, 256, 0, stream>>>(z, e, Cr, eb, out, pt);
        k_finish<<<1, 256, 0, stream>>>(pt, out, NROWS / 64);
    }
}

// Round 18
// 328.540 us; speedup vs baseline: 1.2876x; 1.2876x over previous
//
#include <hip/hip_runtime.h>

#define KCODES 4096
#define DIM    256
#define NROWS  65536
#define MARGIN 4.0e-4f
#define DSLACK 3.0e-5f      // u8 subtile-delta decode slack (quantum 1e-5)
#define LCAP   4096
#define CPAD   32
#define LSTRIDE (DIM + 4)

typedef unsigned long long u64;
typedef unsigned int  uint;
typedef unsigned short ushort;
typedef __attribute__((ext_vector_type(8))) short bf16x8;
typedef __attribute__((ext_vector_type(4))) float f32x4;

typedef __attribute__((address_space(3))) uint lds_u32_t;
typedef __attribute__((address_space(1))) uint glb_u32_t;

__device__ __forceinline__ void g2lds16(const void* g, void* l) {
    __builtin_amdgcn_global_load_lds((const glb_u32_t*)g, (lds_u32_t*)l, 16, 0, 0);
}

// cross-lane mins via DPP (VALU pipe, no LDS)
__device__ __forceinline__ float dppmin_quad(float m) {
    m = fminf(m, __int_as_float(__builtin_amdgcn_update_dpp(0, __float_as_int(m), 0xB1, 0xF, 0xF, true)));
    m = fminf(m, __int_as_float(__builtin_amdgcn_update_dpp(0, __float_as_int(m), 0x4E, 0xF, 0xF, true)));
    return m;
}
__device__ __forceinline__ float dppmin_row16(float m) {
    m = fminf(m, __int_as_float(__builtin_amdgcn_update_dpp(0, __float_as_int(m), 0x124, 0xF, 0xF, true)));
    m = fminf(m, __int_as_float(__builtin_amdgcn_update_dpp(0, __float_as_int(m), 0x128, 0xF, 0xF, true)));
    return m;
}
__device__ __forceinline__ uint dppor_row16(uint v) {
    v |= (uint)__builtin_amdgcn_update_dpp(0, (int)v, 0x124, 0xF, 0xF, true);
    v |= (uint)__builtin_amdgcn_update_dpp(0, (int)v, 0x128, 0xF, 0xF, true);
    return v;
}

// ============================ shared helpers ============================

__device__ __forceinline__ float np_half_sum128(const float4* __restrict__ p4) {
    #pragma clang fp contract(off)
    float4 v0 = p4[0], v1 = p4[1];
    float r0 = v0.x * v0.x, r1 = v0.y * v0.y, r2 = v0.z * v0.z, r3 = v0.w * v0.w;
    float r4 = v1.x * v1.x, r5 = v1.y * v1.y, r6 = v1.z * v1.z, r7 = v1.w * v1.w;
    #pragma unroll
    for (int i = 1; i < 16; ++i) {
        float4 a = p4[2 * i], b = p4[2 * i + 1];
        r0 += a.x * a.x; r1 += a.y * a.y; r2 += a.z * a.z; r3 += a.w * a.w;
        r4 += b.x * b.x; r5 += b.y * b.y; r6 += b.z * b.z; r7 += b.w * b.w;
    }
    return ((r0 + r1) + (r2 + r3)) + ((r4 + r5) + (r6 + r7));
}

__global__ void k_rownorm(const float* __restrict__ src, float* __restrict__ dst, int nrows) {
    int r = blockIdx.x * blockDim.x + threadIdx.x;
    if (r >= nrows) return;
    const float4* p4 = (const float4*)(src + (size_t)r * DIM);
    float s;
    {
        #pragma clang fp contract(off)
        s = np_half_sum128(p4) + np_half_sum128(p4 + 32);
    }
    dst[r] = s;
}

// validated (round 3): fl32( fl32(Cr+ebc) - fl32(2*fl32(cross_exact)) )
__device__ __forceinline__ float f32_dist(float Cr, float ebc, double accv) {
    #pragma clang fp contract(off)
    float A = Cr + ebc;
    float B = 2.0f * (float)accv;
    return A - B;
}

__device__ __forceinline__ ushort f2bf(float f) {
    uint u = __float_as_uint(f);
    return (ushort)((u + 0x7fffu + ((u >> 16) & 1u)) >> 16);
}

__device__ __forceinline__ uint4 pack8(float4 a, float4 b) {
    uint4 ov;
    ov.x = (uint)f2bf(a.x) | ((uint)f2bf(a.y) << 16);
    ov.y = (uint)f2bf(a.z) | ((uint)f2bf(a.w) << 16);
    ov.z = (uint)f2bf(b.x) | ((uint)f2bf(b.y) << 16);
    ov.w = (uint)f2bf(b.z) | ((uint)f2bf(b.w) << 16);
    return ov;
}

// ============================ fast-path kernels ============================

// fused split + np-faithful rownorm: one pass over src.
__global__ void k_prep(const float* __restrict__ src, ushort* __restrict__ dst,
                       float* __restrict__ nrm, int nrows) {
    int r = blockIdx.x * blockDim.x + threadIdx.x;
    if (r >= nrows) return;
    const float4* p4 = (const float4*)(src + (size_t)r * DIM);
    uint4* d4 = (uint4*)(dst + (size_t)r * DIM);
    float h[2];
    #pragma unroll
    for (int half = 0; half < 2; ++half) {
        #pragma clang fp contract(off)
        const float4* p = p4 + half * 32;
        float4 v0 = p[0], v1 = p[1];
        d4[half * 16] = pack8(v0, v1);
        float r0 = v0.x * v0.x, r1 = v0.y * v0.y, r2 = v0.z * v0.z, r3 = v0.w * v0.w;
        float r4 = v1.x * v1.x, r5 = v1.y * v1.y, r6 = v1.z * v1.z, r7 = v1.w * v1.w;
        #pragma unroll
        for (int i = 1; i < 16; ++i) {
            float4 a = p[2 * i], b = p[2 * i + 1];
            d4[half * 16 + i] = pack8(a, b);
            r0 += a.x * a.x; r1 += a.y * a.y; r2 += a.z * a.z; r3 += a.w * a.w;
            r4 += b.x * b.x; r5 += b.y * b.y; r6 += b.z * b.z; r7 += b.w * b.w;
        }
        h[half] = ((r0 + r1) + (r2 + r3)) + ((r4 + r5) + (r6 + r7));
    }
    {
        #pragma clang fp contract(off)
        nrm[r] = h[0] + h[1];
    }
}

__global__ void k_init(int* __restrict__ cnt) {
    cnt[blockIdx.x * 256 + threadIdx.x] = 0;
}

// MFMA filter (round-12 exact version, measured 148us / ~930 TF effective —
// at the plain-HIP 2-barrier structural ceiling): z in regs (32 rows/wave),
// e streamed as 64-code dbuf swizzled LDS tiles (2x32KB, 2 blocks/CU).
// Ping-pong accumulators, deferred Cr-free epilogue; 128-code tk tiles with
// quad (32-code) u8 deltas.
__global__ __launch_bounds__(256, 2)
void k_gemm(const ushort* __restrict__ zh, const ushort* __restrict__ eh,
            const float* __restrict__ Crow, const float* __restrict__ eb2,
            float* __restrict__ tk, uint* __restrict__ tk2) {
    __shared__ __align__(16) ushort Bs[2][64 * 256];   // 2 x 32KB

    const int t = threadIdx.x;
    const int lane = t & 63;
    const int w = t >> 6;
    const int l15 = lane & 15, l4 = lane >> 4;
    const int row0w = blockIdx.x * 128 + w * 32;

    const char* ebp = (const char*)eh;

    auto stage = [&](int buf, int ct2) {
        const char* base = ebp + (size_t)ct2 * 64 * 512;
        #pragma unroll
        for (int i = 0; i < 8; ++i) {
            int idx = i * 256 + t;
            int code = idx >> 5;
            int c16  = idx & 31;
            int src  = (code << 9) + ((c16 ^ (code & 7)) << 4);
            g2lds16(base + src, (char*)Bs[buf] + idx * 16);
        }
    };

    // ---- A: 32 rows x 256 K in registers (MFMA A-frag layout) ----
    bf16x8 a[2][8];
    #pragma unroll
    for (int f = 0; f < 2; ++f)
        #pragma unroll
        for (int ks = 0; ks < 8; ++ks)
            a[f][ks] = *(const bf16x8*)&zh[(size_t)(row0w + f * 16 + l15) * 256 + ks * 32 + l4 * 8];

    float crf[8];
    #pragma unroll
    for (int f = 0; f < 2; ++f)
        #pragma unroll
        for (int rg = 0; rg < 4; ++rg)
            crf[f * 4 + rg] = Crow[row0w + f * 16 + l4 * 4 + rg];

    float mprev[8];
    const f32x4 fzero = (f32x4){0.f, 0.f, 0.f, 0.f};
    f32x4 accA[2][4], accB[2][4];
    float ebvA[4], ebvB[4];

    auto ksloop = [&](const ushort* Bb, f32x4 (&acc)[2][4]) {
        #pragma unroll
        for (int ks = 0; ks < 8; ++ks) {
            bf16x8 bfv[4];
            #pragma unroll
            for (int cg = 0; cg < 4; ++cg) {
                int rB = cg * 16 + l15;
                int off = rB * 256 + ((ks * 32 + l4 * 8) ^ ((l15 & 7) << 3));
                bfv[cg] = *(const bf16x8*)&Bb[off];
            }
            __builtin_amdgcn_s_setprio(1);
            #pragma unroll
            for (int f = 0; f < 2; ++f)
                #pragma unroll
                for (int cg = 0; cg < 4; ++cg)
                    acc[f][cg] = __builtin_amdgcn_mfma_f32_16x16x32_bf16(
                        a[f][ks], bfv[cg], ks == 0 ? fzero : acc[f][cg], 0, 0, 0);
            __builtin_amdgcn_s_setprio(0);
        }
    };

    // deferred epilogue (Cr-free mins; Cr added only at tk store)
    auto epi = [&](f32x4 (&acc)[2][4], const float (&ebv)[4], int ct2, bool odd) {
        #pragma unroll
        for (int f = 0; f < 2; ++f) {
            #pragma unroll
            for (int rg = 0; rg < 4; ++rg) {
                float m =    fmaf(-2.0f, acc[f][0][rg], ebv[0]);
                m = fminf(m, fmaf(-2.0f, acc[f][1][rg], ebv[1]));
                m = fminf(m, fmaf(-2.0f, acc[f][2][rg], ebv[2]));
                m = fminf(m, fmaf(-2.0f, acc[f][3][rg], ebv[3]));
                m = dppmin_quad(m);
                if (!odd) {
                    mprev[f * 4 + rg] = m;
                } else {
                    m = fminf(m, mprev[f * 4 + rg]);
                    float mt = dppmin_row16(m);
                    int q = (int)((m - mt) * 1e5f);    // Cr cancels in m-mt
                    q = q > 255 ? 255 : q;
                    uint pk = (uint)q << (8 * (l15 >> 2));
                    pk = dppor_row16(pk);
                    if (l15 == 0) {
                        int grow = row0w + f * 16 + l4 * 4 + rg;
                        int tt = ct2 >> 1;
                        tk [(size_t)tt * NROWS + grow] = crf[f * 4 + rg] + mt;
                        tk2[(size_t)tt * NROWS + grow] = pk;
                    }
                }
            }
        }
    };

    stage(0, 0);
    #pragma unroll
    for (int cg = 0; cg < 4; ++cg) ebvA[cg] = eb2[cg * 16 + l15];
    __syncthreads();

    for (int tp = 0; tp < 32; ++tp) {
        int t0 = 2 * tp;
        stage(1, t0 + 1);
        if (tp > 0) epi(accB, ebvB, t0 - 1, true);
        ksloop(Bs[0], accA);
        __syncthreads();

        if (tp < 31) stage(0, t0 + 2);
        #pragma unroll
        for (int cg = 0; cg < 4; ++cg) ebvB[cg] = eb2[(t0 + 1) * 64 + cg * 16 + l15];
        epi(accA, ebvA, t0, false);
        if (tp < 31) {
            #pragma unroll
            for (int cg = 0; cg < 4; ++cg) ebvA[cg] = eb2[(t0 + 2) * 64 + cg * 16 + l15];
        }
        ksloop(Bs[1], accB);
        __syncthreads();
    }
    epi(accB, ebvB, 63, true);
}

// per row: rowbest over 32 tile-mins; decode 4 u8 subtile deltas per tile;
// wave-aggregated append; padded counters (1 L2 line each); init fkey.
__global__ void k_lists(const float* __restrict__ tk, const uint* __restrict__ tk2,
                        int* __restrict__ cnt, int* __restrict__ list,
                        u64* __restrict__ fkey) {
    int row = blockIdx.x * 256 + threadIdx.x;
    int lane = threadIdx.x & 63;
    float tm[32]; uint pk[32];
    #pragma unroll
    for (int tt = 0; tt < 32; ++tt) {
        tm[tt] = tk [(size_t)tt * NROWS + row];
        pk[tt] = tk2[(size_t)tt * NROWS + row];
    }
    float best = tm[0];
    #pragma unroll
    for (int tt = 1; tt < 32; ++tt) best = fminf(best, tm[tt]);
    fkey[row] = ~0ull;
    float cutoff = best + (MARGIN + DSLACK);

    #pragma unroll
    for (int tt = 0; tt < 32; ++tt) {
        #pragma unroll
        for (int p = 0; p < 4; ++p) {
            float v = tm[tt] + (float)((pk[tt] >> (8 * p)) & 255u) * 1e-5f;
            bool pred = v <= cutoff;
            u64 mask = __ballot(pred);
            if (mask) {
                int sub = tt * 4 + p;
                int nq = __popcll(mask);
                int rank = __popcll(mask & ((1ull << lane) - 1ull));
                int base = 0;
                if (lane == 0) base = atomicAdd(&cnt[sub * CPAD], nq);
                base = __shfl(base, 0, 64);
                int pos = base + rank;
                if (pred && pos < LCAP) list[sub * LCAP + pos] = row;
            }
        }
    }
}

// exact decider (round-12 version); sub = (tile<<2)|quad:
// codes = tile*128 + cg*16 + quad*4 + r. Validated f64-cross + f32_dist +
// lexicographic (d,idx) key, atomicMin-merged.
__global__ __launch_bounds__(256, 2)
void k_exact(const float* __restrict__ z, const float* __restrict__ e,
             const float* __restrict__ Crow, const float* __restrict__ eb2,
             const int* __restrict__ list, const int* __restrict__ cnt,
             u64* __restrict__ fkey) {
    __shared__ __align__(16) float ex[32][260];
    __shared__ __align__(16) float zx[32][260];
    __shared__ int rows[32];
    __shared__ u64 keytab[32][17];
    const int sub = blockIdx.x;       // 0..127
    const int tile = sub >> 2, qq = sub & 3;
    const int nct = cnt[sub * CPAD];
    const int t = threadIdx.x;
    const int rp = t & 15, cs = t >> 4;

    {   // stage e subtile (32 quad-mapped codes x 256)
        int cc = t >> 3, c8 = t & 7;
        int gcode = tile * 128 + (cc >> 2) * 16 + qq * 4 + (cc & 3);
        const float4* src = (const float4*)(e + (size_t)gcode * DIM);
        float4* dr = (float4*)ex[cc];
        #pragma unroll
        for (int j = 0; j < 8; ++j) dr[c8 + 8 * j] = src[c8 + 8 * j];
    }
    const int gc0 = tile * 128 + (cs >> 2) * 16 + qq * 4 + (cs & 3);
    const int gc1 = tile * 128 + ((cs >> 2) + 4) * 16 + qq * 4 + (cs & 3);
    const float ebc0 = eb2[gc0];
    const float ebc1 = eb2[gc1];

    for (int base = blockIdx.y * 32; base < nct; base += gridDim.y * 32) {
        __syncthreads();
        if (t < 32) {
            int i = base + t;
            rows[t] = list[sub * LCAP + (i < nct ? i : nct - 1)];
        }
        __syncthreads();
        {
            int rr = t >> 3, c8 = t & 7;
            const float4* src = (const float4*)(z + (size_t)rows[rr] * DIM);
            float4* dr = (float4*)zx[rr];
            #pragma unroll
            for (int j = 0; j < 8; ++j) dr[c8 + 8 * j] = src[c8 + 8 * j];
        }
        __syncthreads();

        double a00 = 0.0, a01 = 0.0, a10 = 0.0, a11 = 0.0;
        const float4* z0 = (const float4*)zx[rp];
        const float4* z1 = (const float4*)zx[rp + 16];
        const float4* e0 = (const float4*)ex[cs];
        const float4* e1 = (const float4*)ex[cs + 16];
        #pragma unroll 8
        for (int d4 = 0; d4 < 64; ++d4) {
            float4 x0 = z0[d4], x1 = z1[d4], y0 = e0[d4], y1 = e1[d4];
            a00 += (double)x0.x * (double)y0.x; a00 += (double)x0.y * (double)y0.y;
            a00 += (double)x0.z * (double)y0.z; a00 += (double)x0.w * (double)y0.w;
            a01 += (double)x0.x * (double)y1.x; a01 += (double)x0.y * (double)y1.y;
            a01 += (double)x0.z * (double)y1.z; a01 += (double)x0.w * (double)y1.w;
            a10 += (double)x1.x * (double)y0.x; a10 += (double)x1.y * (double)y0.y;
            a10 += (double)x1.z * (double)y0.z; a10 += (double)x1.w * (double)y0.w;
            a11 += (double)x1.x * (double)y1.x; a11 += (double)x1.y * (double)y1.y;
            a11 += (double)x1.z * (double)y1.z; a11 += (double)x1.w * (double)y1.w;
        }
        int r0 = rows[rp], r1 = rows[rp + 16];
        float C0 = Crow[r0], C1 = Crow[r1];
        u64 k00 = ((u64)__float_as_uint(f32_dist(C0, ebc0, a00)) << 32) | (u64)gc0;
        u64 k01 = ((u64)__float_as_uint(f32_dist(C0, ebc1, a01)) << 32) | (u64)gc1;
        u64 k10 = ((u64)__float_as_uint(f32_dist(C1, ebc0, a10)) << 32) | (u64)gc0;
        u64 k11 = ((u64)__float_as_uint(f32_dist(C1, ebc1, a11)) << 32) | (u64)gc1;
        keytab[rp][cs]      = k00 < k01 ? k00 : k01;
        keytab[rp + 16][cs] = k10 < k11 ? k10 : k11;
        __syncthreads();
        if (t < 32) {
            u64 kb = keytab[t][0];
            #pragma unroll
            for (int j = 1; j < 16; ++j) {
                u64 k = keytab[t][j];
                kb = k < kb ? k : kb;
            }
            atomicMin((unsigned long long*)&fkey[rows[t]], kb);
        }
    }
}

// gather quantized rows + indices; loss partial directly from fkey's exact
// f32 distances (error ~1e-7 relative vs elementwise ref). No z read.
__global__ __launch_bounds__(256)
void k_gather(const float* __restrict__ e, const u64* __restrict__ fkey,
              float* __restrict__ out, double* __restrict__ partial) {
    __shared__ double s[32];
    const int t = threadIdx.x;
    const int row = blockIdx.x * 32 + (t >> 3);
    const int c8 = t & 7;
    u64 key = fkey[row];
    const int idx = (int)(key & 0xffffffffull);
    if (c8 == 0) out[1 + (size_t)NROWS * DIM + row] = (float)idx;
    const float4* er = (const float4*)(e + (size_t)idx * DIM);
    float4* orow = (float4*)(out + 1 + (size_t)row * DIM);
    #pragma unroll
    for (int j = 0; j < 8; ++j) orow[c8 + 8 * j] = er[c8 + 8 * j];
    if (t < 32) {
        u64 k2 = fkey[blockIdx.x * 32 + t];
        s[t] = (double)__uint_as_float((uint)(k2 >> 32));
    }
    __syncthreads();
    if (t == 0) {
        double a = 0.0;
        #pragma unroll
        for (int i = 0; i < 32; ++i) a += s[i];
        partial[blockIdx.x] = a;
    }
}

__global__ void k_finish(const double* __restrict__ partial, float* __restrict__ out, int n) {
    __shared__ double s[256];
    double a = 0.0;
    for (int i = threadIdx.x; i < n; i += 256) a += partial[i];
    s[threadIdx.x] = a;
    __syncthreads();
    for (int off = 128; off > 0; off >>= 1) {
        if (threadIdx.x < off) s[threadIdx.x] += s[threadIdx.x + off];
        __syncthreads();
    }
    if (threadIdx.x == 0)
        out[0] = (float)(1.25 * s[0] / ((double)NROWS * (double)DIM));
}

// ===================== fallback (round-3 validated path) =====================

__global__ __launch_bounds__(256, 1)
void k_main_slow(const float* __restrict__ z, const float* __restrict__ e,
                 const float* __restrict__ Crow, const float* __restrict__ eb2,
                 float* __restrict__ out, double* __restrict__ partial) {
    __shared__ float  zt[64][LSTRIDE];
    __shared__ float  et[64][LSTRIDE];
    __shared__ float  redd[64][17];
    __shared__ int    redi[64][17];
    __shared__ int    bsel[64];
    __shared__ double lred[4];

    const int t  = threadIdx.x;
    const int tx = t & 15;
    const int ty = t >> 4;
    const int row0 = blockIdx.x * 64;

    {
        const float4* zsrc = (const float4*)(z + (size_t)row0 * DIM);
        for (int i = t; i < 64 * (DIM / 4); i += 256) {
            int r = i >> 6, c4 = i & 63;
            *(float4*)&zt[r][c4 * 4] = zsrc[r * (DIM / 4) + c4];
        }
    }
    float Cr[4];
    #pragma unroll
    for (int ri = 0; ri < 4; ++ri) Cr[ri] = Crow[row0 + ty * 4 + ri];
    float bestd[4]; int besti[4];
    #pragma unroll
    for (int ri = 0; ri < 4; ++ri) { bestd[ri] = __int_as_float(0x7f800000); besti[ri] = 0; }

    for (int kt = 0; kt < KCODES / 64; ++kt) {
        __syncthreads();
        {
            const float4* esrc = (const float4*)(e + (size_t)kt * 64 * DIM);
            for (int i = t; i < 64 * (DIM / 4); i += 256) {
                int r = i >> 6, c4 = i & 63;
                *(float4*)&et[r][c4 * 4] = esrc[r * (DIM / 4) + c4];
            }
        }
        __syncthreads();
        double acc[4][4];
        #pragma unroll
        for (int a = 0; a < 4; ++a)
            #pragma unroll
            for (int b = 0; b < 4; ++b) acc[a][b] = 0.0;
        #pragma unroll 4
        for (int d4 = 0; d4 < DIM / 4; ++d4) {
            float4 za[4], ea[4];
            #pragma unroll
            for (int ri = 0; ri < 4; ++ri) za[ri] = *(const float4*)&zt[ty * 4 + ri][d4 * 4];
            #pragma unroll
            for (int ci = 0; ci < 4; ++ci) ea[ci] = *(const float4*)&et[tx + 16 * ci][d4 * 4];
            #pragma unroll
            for (int ri = 0; ri < 4; ++ri)
                #pragma unroll
                for (int ci = 0; ci < 4; ++ci)
                    acc[ri][ci] += (double)za[ri].x * (double)ea[ci].x
                                 + (double)za[ri].y * (double)ea[ci].y
                                 + (double)za[ri].z * (double)ea[ci].z
                                 + (double)za[ri].w * (double)ea[ci].w;
        }
        #pragma unroll
        for (int ci = 0; ci < 4; ++ci) {
            int c = kt * 64 + tx + 16 * ci;
            float ebc = eb2[c];
            #pragma unroll
            for (int ri = 0; ri < 4; ++ri) {
                float d = f32_dist(Cr[ri], ebc, acc[ri][ci]);
                if (d < bestd[ri]) { bestd[ri] = d; besti[ri] = c; }
            }
        }
    }
    __syncthreads();
    #pragma unroll
    for (int ri = 0; ri < 4; ++ri) {
        redd[ty * 4 + ri][tx] = bestd[ri];
        redi[ty * 4 + ri][tx] = besti[ri];
    }
    __syncthreads();
    if (t < 64) {
        float bd = redd[t][0]; int bi = redi[t][0];
        for (int j = 1; j < 16; ++j) {
            float d = redd[t][j]; int i2 = redi[t][j];
            if (d < bd || (d == bd && i2 < bi)) { bd = d; bi = i2; }
        }
        bsel[t] = bi;
        out[1 + (size_t)NROWS * DIM + row0 + t] = (float)bi;
    }
    __syncthreads();
    double lacc = 0.0;
    {
        int r = t >> 2, qd = (t & 3) * 64;
        int bi = bsel[r];
        const float* qrow = e + (size_t)bi * DIM + qd;
        float* orow = out + 1 + (size_t)(row0 + r) * DIM + qd;
        #pragma unroll 4
        for (int d = 0; d < 64; ++d) {
            float qv = qrow[d], zv = zt[r][qd + d];
            double df = (double)qv - (double)zv;
            lacc += df * df;
            orow[d] = qv;
        }
    }
    for (int off = 32; off > 0; off >>= 1) lacc += __shfl_down(lacc, off, 64);
    if ((t & 63) == 0) lred[t >> 6] = lacc;
    __syncthreads();
    if (t == 0) partial[blockIdx.x] = lred[0] + lred[1] + lred[2] + lred[3];
}

// ============================ launch ============================

extern "C" void kernel_launch(void* const* d_in, const int* in_sizes, int n_in,
                              void* d_out, int out_size, void* d_ws, size_t ws_size,
                              hipStream_t stream) {
    const float* z = (const float*)d_in[0];
    const float* e = (const float*)d_in[1];
    float* out = (float*)d_out;
    char* w = (char*)d_ws;

    size_t o = 0;
    auto take = [&](size_t b) { size_t r = o; o = (o + b + 255) & ~(size_t)255; return r; };
    size_t o_zh = take((size_t)NROWS * DIM * 2);
    size_t o_eh = take((size_t)KCODES * DIM * 2);
    size_t o_cr = take((size_t)NROWS * 4);
    size_t o_eb = take((size_t)KCODES * 4);
    size_t o_tk = take((size_t)32 * NROWS * 4);
    size_t o_t2 = take((size_t)32 * NROWS * 4);
    size_t o_fk = take((size_t)NROWS * 8);
    size_t o_cn = take((size_t)128 * CPAD * 4);
    size_t o_ls = take((size_t)128 * LCAP * 4);
    size_t o_pt = take((size_t)2048 * 8);
    size_t need = o;

    if (ws_size >= need) {
        ushort* zh = (ushort*)(w + o_zh);
        ushort* eh = (ushort*)(w + o_eh);
        float* Cr  = (float*)(w + o_cr);
        float* eb  = (float*)(w + o_eb);
        float* tk  = (float*)(w + o_tk);
        uint*  tk2 = (uint*)(w + o_t2);
        u64*   fk  = (u64*)(w + o_fk);
        int*   cn  = (int*)(w + o_cn);
        int*   ls  = (int*)(w + o_ls);
        double* pt = (double*)(w + o_pt);

        k_prep<<<NROWS / 256, 256, 0, stream>>>(z, zh, Cr, NROWS);
        k_prep<<<KCODES / 256, 256, 0, stream>>>(e, eh, eb, KCODES);
        k_init<<<(128 * CPAD) / 256, 256, 0, stream>>>(cn);
        k_gemm<<<NROWS / 128, 256, 0, stream>>>(zh, eh, Cr, eb, tk, tk2);
        k_lists<<<NROWS / 256, 256, 0, stream>>>(tk, tk2, cn, ls, fk);
        dim3 ge(128, 16);
        k_exact<<<ge, 256, 0, stream>>>(z, e, Cr, eb, ls, cn, fk);
        k_gather<<<NROWS / 32, 256, 0, stream>>>(e, fk, out, pt);
        k_finish<<<1, 256, 0, stream>>>(pt, out, 2048);
    } else {
        float* Cr  = (float*)w;
        float* eb  = Cr + NROWS;
        double* pt = (double*)(eb + KCODES);
        k_rownorm<<<NROWS / 256, 256, 0, stream>>>(z, Cr, NROWS);
        k_rownorm<<<KCODES / 256, 256, 0, stream>>>(e, eb, KCODES);
        k_main_slow<<<NROWS / 64, 256, 0, stream>>>(z, e, Cr, eb, out, pt);
        k_finish<<<1, 256, 0, stream>>>(pt, out, NROWS / 64);
    }
}